// Round 4
// baseline (35.626 us; speedup 1.0000x reference)
//
#include <hip/hip_runtime.h>
#include <hip/hip_bf16.h>

// Shapes fixed by the reference: B=8, C=32, H=64, W=512, NCHW.
#define CH   32
#define WD   512
#define NH   64
#define CHST (NH * WD)      // channel stride in floats
#define BST  (CH * CHST)    // batch stride in floats
#define ROWB 1040           // bytes per LDS row (520 bf16; 16B-aligned)

typedef short bf16x8 __attribute__((ext_vector_type(8)));
typedef float f32x16 __attribute__((ext_vector_type(16)));

__device__ __forceinline__ unsigned short f2bf(float f) {
  union { __hip_bfloat16 h; unsigned short u; } cv;
  cv.h = __float2bfloat16(f);
  return cv.u;
}
__device__ __forceinline__ unsigned int pk2(float lo_, float hi_) {
  return ((unsigned int)f2bf(hi_) << 16) | (unsigned int)f2bf(lo_);
}
// v_permlane32_swap_b32 a,b: a' = [a(lanes<32) | b(lanes<32)], b' = [a(lanes>=32) | b(lanes>=32)]
__device__ __forceinline__ void swap32(unsigned int& a, unsigned int& b) {
  asm volatile("v_permlane32_swap_b32 %0, %1" : "+v"(a), "+v"(b));
}

union W4 { unsigned int u[4]; bf16x8 v; };

// ============================ Kernel 1: per-(b,h) G and g ==========================
// kp=Wk*K+bk, vp=Wv*V+bv (bf16 LDS); M[o][c]=sum_x kp[o][x]vp[c][x] (per-wave, K=512);
// G=Wq^T*M (+I residual), g=bq*M.  Stored: G as bf16 A-fragments (b[j]=G[16s+8hi+j][lo]),
// g as f32[32].  MFMA layouts as verified in earlier rounds.
__global__ __launch_bounds__(512, 4)
void k1_Gg(const float* __restrict__ kg, const float* __restrict__ vg,
           const float* __restrict__ wqg, const float* __restrict__ bqg,
           const float* __restrict__ wkg, const float* __restrict__ bkg,
           const float* __restrict__ wvg, const float* __restrict__ bvg,
           unsigned short* __restrict__ GW, float* __restrict__ gw)
{
  __shared__ __align__(16) char kpL[CH * ROWB];
  __shared__ __align__(16) char vpL[CH * ROWB];

  const int t = threadIdx.x, lane = t & 63, wid = t >> 6;
  const int lo = lane & 31, hi = lane >> 5;
  const int bh = blockIdx.x;
  const size_t base = (size_t)(bh >> 6) * BST + (size_t)(bh & 63) * WD;

  int rowr[16];
  #pragma unroll
  for (int r = 0; r < 16; ++r) rowr[r] = (r & 3) + 8 * (r >> 2) + 4 * hi;

  // Wk/Wv A-fragments + biases
  bf16x8 wkA[2], wvA[2];
  {
    const float* wk_r = wkg + lo * CH + 8 * hi;
    const float* wv_r = wvg + lo * CH + 8 * hi;
    #pragma unroll
    for (int s = 0; s < 2; ++s)
      #pragma unroll
      for (int j = 0; j < 8; ++j) {
        wkA[s][j] = (short)f2bf(wk_r[16 * s + j]);
        wvA[s][j] = (short)f2bf(wv_r[16 * s + j]);
      }
  }
  float bkr[16], bvr[16];
  #pragma unroll
  for (int r = 0; r < 16; ++r) { bkr[r] = bkg[rowr[r]]; bvr[r] = bvg[rowr[r]]; }

  // Step A: project k,v -> kp,vp (bf16, swizzled LDS)
  #pragma unroll
  for (int it = 0; it < 2; ++it) {
    const int x0 = 64 * wid + 32 * it;
    float kf[16], vf[16];
    #pragma unroll
    for (int s = 0; s < 2; ++s)
      #pragma unroll
      for (int j = 0; j < 8; ++j) {
        kf[8 * s + j] = kg[base + (size_t)(16 * s + 8 * hi + j) * CHST + x0 + lo];
        vf[8 * s + j] = vg[base + (size_t)(16 * s + 8 * hi + j) * CHST + x0 + lo];
      }
    bf16x8 kb[2], vb[2];
    #pragma unroll
    for (int s = 0; s < 2; ++s)
      #pragma unroll
      for (int j = 0; j < 8; ++j) {
        kb[s][j] = (short)f2bf(kf[8 * s + j]);
        vb[s][j] = (short)f2bf(vf[8 * s + j]);
      }
    f32x16 ka, va;
    #pragma unroll
    for (int r = 0; r < 16; ++r) { ka[r] = bkr[r]; va[r] = bvr[r]; }
    ka = __builtin_amdgcn_mfma_f32_32x32x16_bf16(wkA[0], kb[0], ka, 0, 0, 0);
    ka = __builtin_amdgcn_mfma_f32_32x32x16_bf16(wkA[1], kb[1], ka, 0, 0, 0);
    va = __builtin_amdgcn_mfma_f32_32x32x16_bf16(wvA[0], vb[0], va, 0, 0, 0);
    va = __builtin_amdgcn_mfma_f32_32x32x16_bf16(wvA[1], vb[1], va, 0, 0, 0);
    #pragma unroll
    for (int r = 0; r < 16; ++r) {
      const int row = rowr[r];
      const int off = row * ROWB + ((((x0 + lo) << 1)) ^ (((row >> 3) & 3) << 4));
      *(unsigned short*)(kpL + off) = f2bf(ka[r]);
      *(unsigned short*)(vpL + off) = f2bf(va[r]);
    }
  }

  // Wq A-fragment (issue before the barrier)
  bf16x8 wqA[2];
  {
    float wqf[16];
    #pragma unroll
    for (int s = 0; s < 2; ++s)
      #pragma unroll
      for (int j = 0; j < 8; ++j)
        wqf[8 * s + j] = wqg[(16 * s + 8 * hi + j) * CH + lo];
    #pragma unroll
    for (int s = 0; s < 2; ++s)
      #pragma unroll
      for (int j = 0; j < 8; ++j)
        wqA[s][j] = (short)f2bf(wqf[8 * s + j]);
  }

  __syncthreads();

  // Step B: M = kp * vp^T over full K=512 (per-wave redundant)
  const int swzlo = ((lo >> 3) & 3) << 4;
  f32x16 macc;
  #pragma unroll
  for (int r = 0; r < 16; ++r) macc[r] = 0.f;
  #pragma unroll
  for (int kk = 0; kk < 32; ++kk) {
    const int off = lo * ROWB + ((32 * kk + 16 * hi) ^ swzlo);
    bf16x8 afr = *(const bf16x8*)(kpL + off);
    bf16x8 bfr = *(const bf16x8*)(vpL + off);
    macc = __builtin_amdgcn_mfma_f32_32x32x16_bf16(afr, bfr, macc, 0, 0, 0);
  }

  float bqr[16];
  #pragma unroll
  for (int r = 0; r < 16; ++r) bqr[r] = bqg[rowr[r]];

  // D-layout macc -> B-fragments of M
  W4 mb0, mb1;
  mb0.u[0] = pk2(macc[0], macc[1]);   mb0.u[1] = pk2(macc[2],  macc[3]);
  mb0.u[2] = pk2(macc[4], macc[5]);   mb0.u[3] = pk2(macc[6],  macc[7]);
  swap32(mb0.u[0], mb0.u[2]);         swap32(mb0.u[1], mb0.u[3]);
  mb1.u[0] = pk2(macc[8], macc[9]);   mb1.u[1] = pk2(macc[10], macc[11]);
  mb1.u[2] = pk2(macc[12], macc[13]); mb1.u[3] = pk2(macc[14], macc[15]);
  swap32(mb1.u[0], mb1.u[2]);         swap32(mb1.u[1], mb1.u[3]);

  // Step C: G = Wq^T * M (+I), g = bq * M
  f32x16 gacc;
  #pragma unroll
  for (int r = 0; r < 16; ++r) gacc[r] = 0.f;
  gacc = __builtin_amdgcn_mfma_f32_32x32x16_bf16(wqA[0], mb0.v, gacc, 0, 0, 0);
  gacc = __builtin_amdgcn_mfma_f32_32x32x16_bf16(wqA[1], mb1.v, gacc, 0, 0, 0);
  #pragma unroll
  for (int r = 0; r < 16; ++r)
    if (rowr[r] == lo) gacc[r] += 1.f;          // residual: +I on G's diagonal

  float part = 0.f;
  #pragma unroll
  for (int r = 0; r < 16; ++r) part = fmaf(bqr[r], macc[r], part);
  unsigned int pa = __float_as_uint(part), pb = pa;
  swap32(pa, pb);
  const float gv = __uint_as_float(pa) + __uint_as_float(pb);   // g[lo]

  // G (D-layout) -> A-fragments (bf16)
  W4 ga0, ga1;
  ga0.u[0] = pk2(gacc[0], gacc[1]);   ga0.u[1] = pk2(gacc[2],  gacc[3]);
  ga0.u[2] = pk2(gacc[4], gacc[5]);   ga0.u[3] = pk2(gacc[6],  gacc[7]);
  swap32(ga0.u[0], ga0.u[2]);         swap32(ga0.u[1], ga0.u[3]);
  ga1.u[0] = pk2(gacc[8], gacc[9]);   ga1.u[1] = pk2(gacc[10], gacc[11]);
  ga1.u[2] = pk2(gacc[12], gacc[13]); ga1.u[3] = pk2(gacc[14], gacc[15]);
  swap32(ga1.u[0], ga1.u[2]);         swap32(ga1.u[1], ga1.u[3]);

  // Store G fragments + g (wave 0 only)
  if (wid == 0) {
    const int li = hi * 32 + lo;
    *(bf16x8*)(GW + (size_t)bh * 1024 +       li * 8) = ga0.v;
    *(bf16x8*)(GW + (size_t)bh * 1024 + 512 + li * 8) = ga1.v;
    if (hi == 0) gw[bh * 32 + lo] = gv;
  }
}

// ============================ Kernel 2: out = (G+I)^T * q + g ======================
// 1024 blocks (bh x 2 halves) x 256 threads (4 waves x 64 px). No LDS.
__global__ __launch_bounds__(256, 4)
void k2_out(const float* __restrict__ qg, const unsigned short* __restrict__ GW,
            const float* __restrict__ gw, float* __restrict__ outg)
{
  const int t = threadIdx.x, lane = t & 63, wid = t >> 6;   // wid 0..3
  const int lo = lane & 31, hi = lane >> 5;
  const int bid = blockIdx.x;
  const int bh = bid >> 1, half = bid & 1;
  const size_t base = (size_t)(bh >> 6) * BST + (size_t)(bh & 63) * WD;

  int rowr[16];
  #pragma unroll
  for (int r = 0; r < 16; ++r) rowr[r] = (r & 3) + 8 * (r >> 2) + 4 * hi;

  const int li = hi * 32 + lo;
  bf16x8 ga0 = *(const bf16x8*)(GW + (size_t)bh * 1024 +       li * 8);
  bf16x8 ga1 = *(const bf16x8*)(GW + (size_t)bh * 1024 + 512 + li * 8);
  float gsh[16];
  #pragma unroll
  for (int r = 0; r < 16; ++r) gsh[r] = gw[bh * 32 + rowr[r]];

  // prefetch all 64 q values for this wave's 64 px
  float qpf[32];
  #pragma unroll
  for (int it = 0; it < 2; ++it)
    #pragma unroll
    for (int s = 0; s < 2; ++s)
      #pragma unroll
      for (int j = 0; j < 8; ++j)
        qpf[16 * it + 8 * s + j] =
            qg[base + (size_t)(16 * s + 8 * hi + j) * CHST +
               256 * half + 64 * wid + 32 * it + lo];

  #pragma unroll
  for (int it = 0; it < 2; ++it) {
    const int x0 = 256 * half + 64 * wid + 32 * it;
    bf16x8 qb[2];
    #pragma unroll
    for (int s = 0; s < 2; ++s)
      #pragma unroll
      for (int j = 0; j < 8; ++j)
        qb[s][j] = (short)f2bf(qpf[16 * it + 8 * s + j]);
    f32x16 acc;
    #pragma unroll
    for (int r = 0; r < 16; ++r) acc[r] = gsh[r];
    acc = __builtin_amdgcn_mfma_f32_32x32x16_bf16(ga0, qb[0], acc, 0, 0, 0);
    acc = __builtin_amdgcn_mfma_f32_32x32x16_bf16(ga1, qb[1], acc, 0, 0, 0);
    #pragma unroll
    for (int r = 0; r < 16; ++r)
      outg[base + (size_t)rowr[r] * CHST + x0 + lo] = acc[r];
  }
}

extern "C" void kernel_launch(void* const* d_in, const int* in_sizes, int n_in,
                              void* d_out, int out_size, void* d_ws, size_t ws_size,
                              hipStream_t stream) {
  const float* q  = (const float*)d_in[0];
  const float* k  = (const float*)d_in[1];
  const float* v  = (const float*)d_in[2];
  const float* wq = (const float*)d_in[3];
  const float* bq = (const float*)d_in[4];
  const float* wk = (const float*)d_in[5];
  const float* bk = (const float*)d_in[6];
  const float* wv = (const float*)d_in[7];
  const float* bv = (const float*)d_in[8];
  float* out = (float*)d_out;

  unsigned short* GW = (unsigned short*)d_ws;                        // 512 * 2048 B
  float* gw = (float*)((char*)d_ws + 512 * 2048);                    // 512 * 128 B

  (void)in_sizes; (void)n_in; (void)out_size; (void)ws_size;

  k1_Gg<<<dim3(512), dim3(512), 0, stream>>>(k, v, wq, bq, wk, bk, wv, bv, GW, gw);
  k2_out<<<dim3(1024), dim3(256), 0, stream>>>(q, GW, gw, out);
}

// Round 5
// 29.295 us; speedup vs baseline: 1.2161x; 1.2161x over previous
//
#include <hip/hip_runtime.h>
#include <hip/hip_bf16.h>

// Shapes fixed by the reference: B=8, C=32, H=64, W=512, NCHW.
#define CH   32
#define WD   512
#define NH   64
#define CHST (NH * WD)      // channel stride in floats
#define BST  (CH * CHST)    // batch stride in floats
#define NST  36             // N LDS row stride in f32 (144B: 16B-aligned)

typedef short bf16x8 __attribute__((ext_vector_type(8)));
typedef float f32x16 __attribute__((ext_vector_type(16)));
typedef float f32x8  __attribute__((ext_vector_type(8)));

__device__ __forceinline__ unsigned short f2bf(float f) {
  union { __hip_bfloat16 h; unsigned short u; } cv;
  cv.h = __float2bfloat16(f);
  return cv.u;
}
__device__ __forceinline__ float bf2f(unsigned short u) {
  return __uint_as_float(((unsigned int)u) << 16);
}
__device__ __forceinline__ unsigned int pk2(float lo_, float hi_) {
  return ((unsigned int)f2bf(hi_) << 16) | (unsigned int)f2bf(lo_);
}
// v_permlane32_swap_b32 a,b — round-3-verified half-swap primitive.
__device__ __forceinline__ void swap32(unsigned int& a, unsigned int& b) {
  asm volatile("v_permlane32_swap_b32 %0, %1" : "+v"(a), "+v"(b));
}
union W4 { unsigned int u[4]; bf16x8 v; };

// D-layout f32x16 -> two B-fragments (bf16) of the same matrix (round-3 verified).
__device__ __forceinline__ void d2frag(const f32x16& d, W4& f0, W4& f1) {
  f0.u[0] = pk2(d[0], d[1]);   f0.u[1] = pk2(d[2],  d[3]);
  f0.u[2] = pk2(d[4], d[5]);   f0.u[3] = pk2(d[6],  d[7]);
  swap32(f0.u[0], f0.u[2]);    swap32(f0.u[1], f0.u[3]);
  f1.u[0] = pk2(d[8], d[9]);   f1.u[1] = pk2(d[10], d[11]);
  f1.u[2] = pk2(d[12], d[13]); f1.u[3] = pk2(d[14], d[15]);
  swap32(f1.u[0], f1.u[2]);    swap32(f1.u[1], f1.u[3]);
}
// cross-half sum: returns v(lo,hi=0)+v(lo,hi=1) on all lanes (round-3 verified).
__device__ __forceinline__ float halfsum(float v) {
  unsigned int a = __float_as_uint(v), b = a;
  swap32(a, b);
  return __uint_as_float(a) + __uint_as_float(b);
}

// One block per (b,h). N = K*V^T computed directly from raw inputs (no staging).
//   M = Wk*N*Wv^T + (Wk sK) bv^T + bk (Wv sV + 512 bv)^T
//   G = Wq^T*M (+I residual), g = bq*M;  out = G^T q + g.
// MFMA 32x32x16 layouts (verified rounds 2-4): A: a[s][j]=A[lo][16s+8hi+j];
// B: b[s][j]=B[16s+8hi+j][lo]; D: d[r]=D[(r&3)+8(r>>2)+4hi][lo].
__global__ __launch_bounds__(512, 4)
void fused_mha(const float* __restrict__ qg, const float* __restrict__ kg,
               const float* __restrict__ vg,
               const float* __restrict__ wqg, const float* __restrict__ bqg,
               const float* __restrict__ wkg, const float* __restrict__ bkg,
               const float* __restrict__ wvg, const float* __restrict__ bvg,
               float* __restrict__ outg)
{
  __shared__ float np[8][CH][NST];   // per-wave partial N; np[0] = reduced N
  __shared__ float sp[8][2][CH];     // per-wave partial sK,sV; sp[0] = reduced

  const int t = threadIdx.x, lane = t & 63, wid = t >> 6;
  const int lo = lane & 31, hi = lane >> 5;
  const int bh = blockIdx.x;
  const size_t base = (size_t)(bh >> 6) * BST + (size_t)(bh & 63) * WD;

  int rowr[16];
  #pragma unroll
  for (int r = 0; r < 16; ++r) rowr[r] = (r & 3) + 8 * (r >> 2) + 4 * hi;

  // Wk/Wv A-fragments (bf16) — wv also serves as B-frag of Wv^T in phase 3.
  bf16x8 wkA[2], wvA[2];
  {
    const float* wk_r = wkg + lo * CH + 8 * hi;
    const float* wv_r = wvg + lo * CH + 8 * hi;
    #pragma unroll
    for (int s = 0; s < 2; ++s)
      #pragma unroll
      for (int j = 0; j < 8; ++j) {
        wkA[s][j] = (short)f2bf(wk_r[16 * s + j]);
        wvA[s][j] = (short)f2bf(wv_r[16 * s + j]);
      }
  }

  // ---- Phase 1: stream this wave's x-slice of k,v; N partial + sK/sV partial ------
  const float* krow = kg + base + (size_t)lo * CHST + 64 * wid + 8 * hi;
  const float* vrow = vg + base + (size_t)lo * CHST + 64 * wid + 8 * hi;
  f32x8 kf[4], vf[4];
  #pragma unroll
  for (int kk = 0; kk < 4; ++kk) {
    kf[kk] = *(const f32x8*)(krow + 16 * kk);
    vf[kk] = *(const f32x8*)(vrow + 16 * kk);
  }
  f32x16 nacc;
  #pragma unroll
  for (int r = 0; r < 16; ++r) nacc[r] = 0.f;
  float psK = 0.f, psV = 0.f;
  #pragma unroll
  for (int kk = 0; kk < 4; ++kk) {
    W4 kb, vb;
    #pragma unroll
    for (int i = 0; i < 4; ++i) {
      kb.u[i] = pk2(kf[kk][2 * i], kf[kk][2 * i + 1]);
      vb.u[i] = pk2(vf[kk][2 * i], vf[kk][2 * i + 1]);
    }
    nacc = __builtin_amdgcn_mfma_f32_32x32x16_bf16(kb.v, vb.v, nacc, 0, 0, 0);
    #pragma unroll
    for (int j = 0; j < 8; ++j) { psK += kf[kk][j]; psV += vf[kk][j]; }
  }
  #pragma unroll
  for (int r = 0; r < 16; ++r) np[wid][rowr[r]][lo] = nacc[r];
  {
    const float sk = halfsum(psK), sv = halfsum(psV);
    if (hi == 0) { sp[wid][0][lo] = sk; sp[wid][1][lo] = sv; }
  }
  __syncthreads();

  // ---- Reduce 8 partials (in place into np[0], sp[0]) -----------------------------
  {
    #pragma unroll
    for (int p = 0; p < 2; ++p) {
      const int e = t + 512 * p, o = e >> 5, c = e & 31;
      float s = 0.f;
      #pragma unroll
      for (int w = 0; w < 8; ++w) s += np[w][o][c];
      np[0][o][c] = s;
    }
    if (t < 64) {
      const int j = t >> 5, o = t & 31;
      float s = 0.f;
      #pragma unroll
      for (int w = 0; w < 8; ++w) s += sp[w][j][o];
      sp[0][j][o] = s;
    }
  }
  __syncthreads();

  // ---- q prefetch: latency hides under the register compute chain -----------------
  float qpf[32];
  #pragma unroll
  for (int it = 0; it < 2; ++it)
    #pragma unroll
    for (int s = 0; s < 2; ++s)
      #pragma unroll
      for (int j = 0; j < 8; ++j)
        qpf[16 * it + 8 * s + j] =
            qg[base + (size_t)(16 * s + 8 * hi + j) * CHST + 64 * wid + 32 * it + lo];

  // Wq A-fragment (A of Wq^T), biases
  bf16x8 wqA[2];
  {
    #pragma unroll
    for (int s = 0; s < 2; ++s)
      #pragma unroll
      for (int j = 0; j < 8; ++j)
        wqA[s][j] = (short)f2bf(wqg[(16 * s + 8 * hi + j) * CH + lo]);
  }
  float bkr[16], bqr[16];
  #pragma unroll
  for (int r = 0; r < 16; ++r) { bkr[r] = bkg[rowr[r]]; bqr[r] = bqg[rowr[r]]; }
  const float bvlo = bvg[lo];

  // ---- Phase 3 (per-wave redundant, all in registers) -----------------------------
  // N A-fragments, hi/lo split (error-free N path).
  W4 NAh[2], NAl[2];
  #pragma unroll
  for (int s = 0; s < 2; ++s) {
    f32x8 nf = *(const f32x8*)&np[0][lo][16 * s + 8 * hi];
    #pragma unroll
    for (int i = 0; i < 4; ++i) {
      const float x = nf[2 * i], y = nf[2 * i + 1];
      const unsigned short hx = f2bf(x), hy = f2bf(y);
      NAh[s].u[i] = ((unsigned int)hy << 16) | hx;
      NAl[s].u[i] = pk2(x - bf2f(hx), y - bf2f(hy));
    }
  }
  // P = N * Wv^T
  f32x16 pacc;
  #pragma unroll
  for (int r = 0; r < 16; ++r) pacc[r] = 0.f;
  pacc = __builtin_amdgcn_mfma_f32_32x32x16_bf16(NAh[0].v, wvA[0], pacc, 0, 0, 0);
  pacc = __builtin_amdgcn_mfma_f32_32x32x16_bf16(NAh[1].v, wvA[1], pacc, 0, 0, 0);
  pacc = __builtin_amdgcn_mfma_f32_32x32x16_bf16(NAl[0].v, wvA[0], pacc, 0, 0, 0);
  pacc = __builtin_amdgcn_mfma_f32_32x32x16_bf16(NAl[1].v, wvA[1], pacc, 0, 0, 0);
  // P' = P + sK * bv^T
  f32x16 pp;
  #pragma unroll
  for (int r = 0; r < 16; ++r) pp[r] = pacc[r] + sp[0][0][rowr[r]] * bvlo;
  // u[lo] = (Wv sV)[lo] + 512*bv[lo]
  float uprt = 0.f;
  #pragma unroll
  for (int s = 0; s < 2; ++s)
    #pragma unroll
    for (int j = 0; j < 8; ++j)
      uprt += bf2f((unsigned short)wvA[s][j]) * sp[0][1][16 * s + 8 * hi + j];
  const float uful = halfsum(uprt) + 512.f * bvlo;
  // M = Wk * P' (hi/lo) + bk * u^T     (D-layout)
  f32x16 pres;
  #pragma unroll
  for (int r = 0; r < 16; ++r) pres[r] = pp[r] - bf2f(f2bf(pp[r]));
  W4 pb0h, pb1h, pb0l, pb1l;
  d2frag(pp, pb0h, pb1h);
  d2frag(pres, pb0l, pb1l);
  f32x16 mac;
  #pragma unroll
  for (int r = 0; r < 16; ++r) mac[r] = bkr[r] * uful;
  mac = __builtin_amdgcn_mfma_f32_32x32x16_bf16(wkA[0], pb0h.v, mac, 0, 0, 0);
  mac = __builtin_amdgcn_mfma_f32_32x32x16_bf16(wkA[1], pb1h.v, mac, 0, 0, 0);
  mac = __builtin_amdgcn_mfma_f32_32x32x16_bf16(wkA[0], pb0l.v, mac, 0, 0, 0);
  mac = __builtin_amdgcn_mfma_f32_32x32x16_bf16(wkA[1], pb1l.v, mac, 0, 0, 0);
  // G = Wq^T * M (+I), g = bq * M
  W4 mb0, mb1;
  d2frag(mac, mb0, mb1);
  f32x16 gacc;
  #pragma unroll
  for (int r = 0; r < 16; ++r) gacc[r] = 0.f;
  gacc = __builtin_amdgcn_mfma_f32_32x32x16_bf16(wqA[0], mb0.v, gacc, 0, 0, 0);
  gacc = __builtin_amdgcn_mfma_f32_32x32x16_bf16(wqA[1], mb1.v, gacc, 0, 0, 0);
  #pragma unroll
  for (int r = 0; r < 16; ++r)
    if (rowr[r] == lo) gacc[r] += 1.f;            // residual: +I on G's diagonal
  float part = 0.f;
  #pragma unroll
  for (int r = 0; r < 16; ++r) part = fmaf(bqr[r], mac[r], part);
  const float gv = halfsum(part);                  // g[lo]
  // G (D-layout) -> fragments usable as A of G^T
  W4 ga0, ga1;
  d2frag(gacc, ga0, ga1);
  float gsh[16];
  #pragma unroll
  for (int r = 0; r < 16; ++r) gsh[r] = __shfl(gv, rowr[r], 64);

  // ---- Phase 4: out = G^T * q + g --------------------------------------------------
  #pragma unroll
  for (int it = 0; it < 2; ++it) {
    const int x0 = 64 * wid + 32 * it;
    bf16x8 qb[2];
    #pragma unroll
    for (int s = 0; s < 2; ++s)
      #pragma unroll
      for (int j = 0; j < 8; ++j)
        qb[s][j] = (short)f2bf(qpf[16 * it + 8 * s + j]);
    f32x16 acc;
    #pragma unroll
    for (int r = 0; r < 16; ++r) acc[r] = gsh[r];
    acc = __builtin_amdgcn_mfma_f32_32x32x16_bf16(ga0.v, qb[0], acc, 0, 0, 0);
    acc = __builtin_amdgcn_mfma_f32_32x32x16_bf16(ga1.v, qb[1], acc, 0, 0, 0);
    #pragma unroll
    for (int r = 0; r < 16; ++r)
      outg[base + (size_t)rowr[r] * CHST + x0 + lo] = acc[r];
  }
}

extern "C" void kernel_launch(void* const* d_in, const int* in_sizes, int n_in,
                              void* d_out, int out_size, void* d_ws, size_t ws_size,
                              hipStream_t stream) {
  const float* q  = (const float*)d_in[0];
  const float* k  = (const float*)d_in[1];
  const float* v  = (const float*)d_in[2];
  const float* wq = (const float*)d_in[3];
  const float* bq = (const float*)d_in[4];
  const float* wk = (const float*)d_in[5];
  const float* bk = (const float*)d_in[6];
  const float* wv = (const float*)d_in[7];
  const float* bv = (const float*)d_in[8];
  float* out = (float*)d_out;

  (void)in_sizes; (void)n_in; (void)out_size; (void)d_ws; (void)ws_size;

  fused_mha<<<dim3(8 * 64), dim3(512), 0, stream>>>(q, k, v, wq, bq, wk, bk, wv, bv, out);
}